// Round 5
// baseline (2826.907 us; speedup 1.0000x reference)
//
#include <hip/hip_runtime.h>
#include <math.h>

#define N_NODES 100000
#define N_EDGES 1600000
#define IN_C 128
#define HID_C 128
#define OUT_C 64
#define NLAYERS 4
#define KSTEPS 10
#define ALPHA 0.1f
#define LN_EPS 1e-5f

#define SCAN_N (N_NODES + 1)
#define SCAN_BLOCKS ((SCAN_N + 1023) / 1024)     // 98
#define EP_CAP 2400000                            // 1.6M edges + <=7 pad/node

__device__ __forceinline__ float gelu_exact(float x) {
    return 0.5f * x * (1.0f + erff(x * 0.70710678118654752f));
}

// Pack two fp32 into bf16x2 (round-to-nearest-even). a -> low (ch 2l), b -> high.
__device__ __forceinline__ unsigned pack_bf16_rne(float a, float b) {
    unsigned ua = __float_as_uint(a);
    unsigned ub = __float_as_uint(b);
    ua = (ua + 0x7fffu + ((ua >> 16) & 1u)) >> 16;
    ub = (ub + 0x7fffu + ((ub >> 16) & 1u)) >> 16;
    return (ub << 16) | ua;
}
__device__ __forceinline__ float bf_lo(unsigned d) { return __uint_as_float(d << 16); }
__device__ __forceinline__ float bf_hi(unsigned d) { return __uint_as_float(d & 0xffff0000u); }

// ---------------------------------------------------------------------------
// CSR build: count in-degree per dst
__global__ void count_k(const int* __restrict__ dst, int* __restrict__ counts) {
    int e = blockIdx.x * blockDim.x + threadIdx.x;
    if (e < N_EDGES) atomicAdd(&counts[dst[e]], 1);
}

// scan1: per-block sums of padded (x8) counts
__global__ __launch_bounds__(1024) void scan1_k(const int* __restrict__ counts,
                                                int* __restrict__ bsum) {
    __shared__ int s[1024];
    int i = blockIdx.x * 1024 + threadIdx.x;
    int c = 0;
    if (i < N_NODES) c = (counts[i] + 7) & ~7;
    s[threadIdx.x] = c;
    __syncthreads();
    for (int off = 512; off; off >>= 1) {
        if (threadIdx.x < off) s[threadIdx.x] += s[threadIdx.x + off];
        __syncthreads();
    }
    if (threadIdx.x == 0) bsum[blockIdx.x] = s[0];
}

// scan2: exclusive scan of the 98 block sums
__global__ void scan2_k(int* __restrict__ bsum) {
    __shared__ int s[128];
    int t = threadIdx.x;
    s[t] = (t < SCAN_BLOCKS) ? bsum[t] : 0;
    __syncthreads();
    for (int off = 1; off < 128; off <<= 1) {
        int v = (t >= off) ? s[t - off] : 0;
        __syncthreads();
        s[t] += v;
        __syncthreads();
    }
    if (t < SCAN_BLOCKS) bsum[t] = (t == 0) ? 0 : s[t - 1];
}

// scan3: per-block exclusive scan + block offset -> row_off / fill_pos
__global__ __launch_bounds__(1024) void scan3_k(const int* __restrict__ counts,
                                                const int* __restrict__ bsum,
                                                int* __restrict__ row_off,
                                                int* __restrict__ fill_pos) {
    __shared__ int s[1024];
    int i = blockIdx.x * 1024 + threadIdx.x;
    int c = 0;
    if (i < N_NODES) c = (counts[i] + 7) & ~7;
    s[threadIdx.x] = c;
    __syncthreads();
    for (int off = 1; off < 1024; off <<= 1) {
        int v = (threadIdx.x >= off) ? s[threadIdx.x - off] : 0;
        __syncthreads();
        s[threadIdx.x] += v;
        __syncthreads();
    }
    if (i <= N_NODES) {
        int excl = s[threadIdx.x] - c + bsum[blockIdx.x];
        row_off[i] = excl;
        fill_pos[i] = excl;
    }
}

// Bucket edges by dst; pack (src*64 [dword offset of bf16x2 row], (1-alpha)*w).
// Pad slots stay (0,0.0f) from the ep memset -> gather row 0 * 0 -> no-op.
// (8-pass range-restricted variant measured neutral vs single pass: r2 2799
//  vs r4 2811 us -> keep the single pass, 7 fewer 6.4 MB dst scans.)
__global__ void bucket_k(const int* __restrict__ src, const int* __restrict__ dst,
                         const float* __restrict__ w,
                         int* __restrict__ fill_pos, int2* __restrict__ ep) {
    int e = blockIdx.x * blockDim.x + threadIdx.x;
    if (e >= N_EDGES) return;
    int d = dst[e];
    int pos = atomicAdd(&fill_pos[d], 1);
    float ws = (1.0f - ALPHA) * w[e];
    ep[pos] = make_int2(src[e] << 6, __float_as_int(ws));
}

// ---------------------------------------------------------------------------
// Encoder: H(bf16) = gelu(LN(x @ Wenc^T)).
// block=1024 (16 waves); wave: 4 rows; lane holds channel pair (2l, 2l+1).
// Weights in LDS as TWO float tables (even/odd channel) with 4 B lane stride:
// the previous float2 table (8 B stride) was a 4-way bank conflict on every
// read (262144 SQ_LDS_BANK_CONFLICT/dispatch, m136: 1.58x cost).
__global__ __launch_bounds__(1024) void encoder_k(
        const float* __restrict__ x, const float* __restrict__ Wenc,
        const float* __restrict__ gamma, const float* __restrict__ beta,
        unsigned* __restrict__ H) {
    __shared__ float WTe[IN_C * 65];           // WTe[k*65 + l] = W[2l][k]
    __shared__ float WTo[IN_C * 65];           // WTo[k*65 + l] = W[2l+1][k]
    __shared__ float XS[16][512];              // per-wave 4-row x tile
    for (int i = threadIdx.x; i < IN_C * HID_C; i += 1024) {
        int c = i >> 7, k = i & 127;
        float v = Wenc[i];
        if (c & 1) WTo[k * 65 + (c >> 1)] = v;
        else       WTe[k * 65 + (c >> 1)] = v;
    }
    __syncthreads();
    int lane = threadIdx.x & 63;
    int wid  = threadIdx.x >> 6;
    float2 gb = ((const float2*)gamma)[lane];
    float2 bb = ((const float2*)beta)[lane];
    int wstride = gridDim.x * 16;
    float* xs = XS[wid];
    for (int grp = blockIdx.x * 16 + wid; grp * 4 < N_NODES; grp += wstride) {
        int r0 = grp * 4;
        const float4* xr = (const float4*)(x + (size_t)r0 * IN_C);
        ((float4*)xs)[lane]      = xr[lane];        // rows r0, r0+1
        ((float4*)xs)[64 + lane] = xr[64 + lane];   // rows r0+2, r0+3
        __builtin_amdgcn_wave_barrier();            // wave-private: no block barrier
        float a0x = 0, a0y = 0, a1x = 0, a1y = 0;
        float a2x = 0, a2y = 0, a3x = 0, a3y = 0;
        const float4* xs4 = (const float4*)xs;
#pragma unroll 4
        for (int k4 = 0; k4 < 32; ++k4) {
            float4 xv0 = xs4[k4];
            float4 xv1 = xs4[32 + k4];
            float4 xv2 = xs4[64 + k4];
            float4 xv3 = xs4[96 + k4];
            int k = k4 * 4;
            const float* pe = &WTe[k * 65 + lane];
            const float* po = &WTo[k * 65 + lane];
            float we0 = pe[0],   wo0 = po[0];
            float we1 = pe[65],  wo1 = po[65];
            float we2 = pe[130], wo2 = po[130];
            float we3 = pe[195], wo3 = po[195];
#define ENC_ROW(ax, ay, xv)                                      \
            ax = fmaf(xv.x, we0, ax); ay = fmaf(xv.x, wo0, ay);   \
            ax = fmaf(xv.y, we1, ax); ay = fmaf(xv.y, wo1, ay);   \
            ax = fmaf(xv.z, we2, ax); ay = fmaf(xv.z, wo2, ay);   \
            ax = fmaf(xv.w, we3, ax); ay = fmaf(xv.w, wo3, ay);
            ENC_ROW(a0x, a0y, xv0)
            ENC_ROW(a1x, a1y, xv1)
            ENC_ROW(a2x, a2y, xv2)
            ENC_ROW(a3x, a3y, xv3)
#undef ENC_ROW
        }
        __builtin_amdgcn_wave_barrier();
#define ENC_EPI(ax, ay, row)                                               \
        {                                                                   \
            float sum = ax + ay;                                            \
            for (int off = 32; off; off >>= 1) sum += __shfl_xor(sum, off); \
            float mu = sum * (1.0f / 128.0f);                               \
            float d0 = ax - mu, d1 = ay - mu;                               \
            float vs = d0 * d0 + d1 * d1;                                   \
            for (int off = 32; off; off >>= 1) vs += __shfl_xor(vs, off);   \
            float inv = rsqrtf(vs * (1.0f / 128.0f) + LN_EPS);              \
            float o0 = gelu_exact(gb.x * d0 * inv + bb.x);                  \
            float o1 = gelu_exact(gb.y * d1 * inv + bb.y);                  \
            H[(size_t)(row)*64 + lane] = pack_bf16_rne(o0, o1);             \
        }
        ENC_EPI(a0x, a0y, r0)
        ENC_EPI(a1x, a1y, r0 + 1)
        ENC_EPI(a2x, a2y, r0 + 2)
        ENC_EPI(a3x, a3y, r0 + 3)
#undef ENC_EPI
    }
}

// ---------------------------------------------------------------------------
// One APPNP step (pull), bf16 features. Wave per node; lane holds channel pair
// (2l, 2l+1) as one bf16x2 dword -> 256 B/row gathers.
// Edge (offset, weight) broadcast via v_readlane -> SGPR (saddr-form loads,
// zero per-edge address VALU, no DS traffic). 16-deep unroll (measured equal
// to 8-deep -> prop is bound by cache-side gather traffic, not MLP:
// 410 MB/step at ~6.6 TB/s effective = 62 us/step plateau across 3 variants).
// Accumulate fp32; store bf16 (RNE). fuse_ln: gelu+LN on the last K-step.
__global__ __launch_bounds__(256) void prop_k(
        const unsigned* __restrict__ zin, const unsigned* __restrict__ x0,
        const int* __restrict__ row_off, const int2* __restrict__ ep,
        unsigned* __restrict__ zout, int fuse_ln,
        const float* __restrict__ gamma, const float* __restrict__ beta) {
    int gw = (blockIdx.x * 256 + threadIdx.x) >> 6;   // node id
    if (gw >= N_NODES) return;
    int lane = threadIdx.x & 63;
    int s0 = row_off[gw];
    int s1 = row_off[gw + 1];                          // padded degree (x8)
    unsigned xd = x0[(size_t)gw * 64 + lane];          // prefetch alpha-term row
    float sx = 0.f, sy = 0.f;
    for (int base = s0; base < s1; base += 64) {
        int cnt = min(64, s1 - base);                  // multiple of 8
        int2 p = make_int2(0, 0);
        if (lane < cnt) p = ep[base + lane];
        int j = 0;
#define EDGE(k, ov, wv)                                                     \
        int   ov = __builtin_amdgcn_readlane(p.x, j + k);                   \
        float wv = __uint_as_float(                                         \
            (unsigned)__builtin_amdgcn_readlane(p.y, j + k));
        for (; j + 16 <= cnt; j += 16) {
            EDGE(0,  o0,  w0)  EDGE(1,  o1,  w1)  EDGE(2,  o2,  w2)
            EDGE(3,  o3,  w3)  EDGE(4,  o4,  w4)  EDGE(5,  o5,  w5)
            EDGE(6,  o6,  w6)  EDGE(7,  o7,  w7)  EDGE(8,  o8,  w8)
            EDGE(9,  o9,  w9)  EDGE(10, o10, w10) EDGE(11, o11, w11)
            EDGE(12, o12, w12) EDGE(13, o13, w13) EDGE(14, o14, w14)
            EDGE(15, o15, w15)
            unsigned d0  = zin[o0  + lane];
            unsigned d1  = zin[o1  + lane];
            unsigned d2  = zin[o2  + lane];
            unsigned d3  = zin[o3  + lane];
            unsigned d4  = zin[o4  + lane];
            unsigned d5  = zin[o5  + lane];
            unsigned d6  = zin[o6  + lane];
            unsigned d7  = zin[o7  + lane];
            unsigned d8  = zin[o8  + lane];
            unsigned d9  = zin[o9  + lane];
            unsigned d10 = zin[o10 + lane];
            unsigned d11 = zin[o11 + lane];
            unsigned d12 = zin[o12 + lane];
            unsigned d13 = zin[o13 + lane];
            unsigned d14 = zin[o14 + lane];
            unsigned d15 = zin[o15 + lane];
            sx = fmaf(w0,  bf_lo(d0),  sx); sy = fmaf(w0,  bf_hi(d0),  sy);
            sx = fmaf(w1,  bf_lo(d1),  sx); sy = fmaf(w1,  bf_hi(d1),  sy);
            sx = fmaf(w2,  bf_lo(d2),  sx); sy = fmaf(w2,  bf_hi(d2),  sy);
            sx = fmaf(w3,  bf_lo(d3),  sx); sy = fmaf(w3,  bf_hi(d3),  sy);
            sx = fmaf(w4,  bf_lo(d4),  sx); sy = fmaf(w4,  bf_hi(d4),  sy);
            sx = fmaf(w5,  bf_lo(d5),  sx); sy = fmaf(w5,  bf_hi(d5),  sy);
            sx = fmaf(w6,  bf_lo(d6),  sx); sy = fmaf(w6,  bf_hi(d6),  sy);
            sx = fmaf(w7,  bf_lo(d7),  sx); sy = fmaf(w7,  bf_hi(d7),  sy);
            sx = fmaf(w8,  bf_lo(d8),  sx); sy = fmaf(w8,  bf_hi(d8),  sy);
            sx = fmaf(w9,  bf_lo(d9),  sx); sy = fmaf(w9,  bf_hi(d9),  sy);
            sx = fmaf(w10, bf_lo(d10), sx); sy = fmaf(w10, bf_hi(d10), sy);
            sx = fmaf(w11, bf_lo(d11), sx); sy = fmaf(w11, bf_hi(d11), sy);
            sx = fmaf(w12, bf_lo(d12), sx); sy = fmaf(w12, bf_hi(d12), sy);
            sx = fmaf(w13, bf_lo(d13), sx); sy = fmaf(w13, bf_hi(d13), sy);
            sx = fmaf(w14, bf_lo(d14), sx); sy = fmaf(w14, bf_hi(d14), sy);
            sx = fmaf(w15, bf_lo(d15), sx); sy = fmaf(w15, bf_hi(d15), sy);
        }
        if (j < cnt) {                                 // exactly 8 remain
            EDGE(0, o0, w0) EDGE(1, o1, w1) EDGE(2, o2, w2) EDGE(3, o3, w3)
            EDGE(4, o4, w4) EDGE(5, o5, w5) EDGE(6, o6, w6) EDGE(7, o7, w7)
            unsigned d0 = zin[o0 + lane];
            unsigned d1 = zin[o1 + lane];
            unsigned d2 = zin[o2 + lane];
            unsigned d3 = zin[o3 + lane];
            unsigned d4 = zin[o4 + lane];
            unsigned d5 = zin[o5 + lane];
            unsigned d6 = zin[o6 + lane];
            unsigned d7 = zin[o7 + lane];
            sx = fmaf(w0, bf_lo(d0), sx); sy = fmaf(w0, bf_hi(d0), sy);
            sx = fmaf(w1, bf_lo(d1), sx); sy = fmaf(w1, bf_hi(d1), sy);
            sx = fmaf(w2, bf_lo(d2), sx); sy = fmaf(w2, bf_hi(d2), sy);
            sx = fmaf(w3, bf_lo(d3), sx); sy = fmaf(w3, bf_hi(d3), sy);
            sx = fmaf(w4, bf_lo(d4), sx); sy = fmaf(w4, bf_hi(d4), sy);
            sx = fmaf(w5, bf_lo(d5), sx); sy = fmaf(w5, bf_hi(d5), sy);
            sx = fmaf(w6, bf_lo(d6), sx); sy = fmaf(w6, bf_hi(d6), sy);
            sx = fmaf(w7, bf_lo(d7), sx); sy = fmaf(w7, bf_hi(d7), sy);
        }
#undef EDGE
    }
    float zx = fmaf(ALPHA, bf_lo(xd), sx);
    float zy = fmaf(ALPHA, bf_hi(xd), sy);
    unsigned od;
    if (fuse_ln) {
        float h0 = gelu_exact(zx);
        float h1 = gelu_exact(zy);
        float sum = h0 + h1;
        for (int off = 32; off; off >>= 1) sum += __shfl_xor(sum, off);
        float mu = sum * (1.0f / 128.0f);
        float d0 = h0 - mu, d1 = h1 - mu;
        float vs = d0 * d0 + d1 * d1;
        for (int off = 32; off; off >>= 1) vs += __shfl_xor(vs, off);
        float inv = rsqrtf(vs * (1.0f / 128.0f) + LN_EPS);
        float2 gb = ((const float2*)gamma)[lane];
        float2 bb = ((const float2*)beta)[lane];
        od = pack_bf16_rne(gb.x * d0 * inv + bb.x, gb.y * d1 * inv + bb.y);
    } else {
        od = pack_bf16_rne(zx, zy);
    }
    zout[(size_t)gw * 64 + lane] = od;
}

// ---------------------------------------------------------------------------
// Decoder: out(fp32) = H(bf16) @ Wdec^T -> [N, 64].
__global__ __launch_bounds__(1024) void decoder_k(
        const unsigned* __restrict__ H, const float* __restrict__ Wdec,
        float* __restrict__ out) {
    __shared__ float WT[HID_C * 65];           // WT[k*65 + o]
    __shared__ unsigned XS[16][256];
    for (int i = threadIdx.x; i < OUT_C * HID_C; i += 1024) {
        int o = i >> 7, k = i & 127;
        WT[k * 65 + o] = Wdec[i];
    }
    __syncthreads();
    int lane = threadIdx.x & 63;
    int wid  = threadIdx.x >> 6;
    int wstride = gridDim.x * 16;
    unsigned* xs = XS[wid];
    for (int grp = blockIdx.x * 16 + wid; grp * 4 < N_NODES; grp += wstride) {
        int r0 = grp * 4;
        const unsigned* hp = H + (size_t)r0 * 64;
        xs[lane]       = hp[lane];
        xs[64 + lane]  = hp[64 + lane];
        xs[128 + lane] = hp[128 + lane];
        xs[192 + lane] = hp[192 + lane];
        __builtin_amdgcn_wave_barrier();
        float a0 = 0, a1 = 0, a2 = 0, a3 = 0;
#pragma unroll 4
        for (int k2 = 0; k2 < 64; ++k2) {      // channel-pair index
            float w0 = WT[(2 * k2) * 65 + lane];
            float w1 = WT[(2 * k2 + 1) * 65 + lane];
            unsigned u0 = xs[k2];
            unsigned u1 = xs[64 + k2];
            unsigned u2 = xs[128 + k2];
            unsigned u3 = xs[192 + k2];
            a0 = fmaf(bf_lo(u0), w0, a0); a0 = fmaf(bf_hi(u0), w1, a0);
            a1 = fmaf(bf_lo(u1), w0, a1); a1 = fmaf(bf_hi(u1), w1, a1);
            a2 = fmaf(bf_lo(u2), w0, a2); a2 = fmaf(bf_hi(u2), w1, a2);
            a3 = fmaf(bf_lo(u3), w0, a3); a3 = fmaf(bf_hi(u3), w1, a3);
        }
        __builtin_amdgcn_wave_barrier();
        out[(size_t)r0 * OUT_C + lane]       = a0;
        out[(size_t)(r0 + 1) * OUT_C + lane] = a1;
        out[(size_t)(r0 + 2) * OUT_C + lane] = a2;
        out[(size_t)(r0 + 3) * OUT_C + lane] = a3;
    }
}

// ---------------------------------------------------------------------------
extern "C" void kernel_launch(void* const* d_in, const int* in_sizes, int n_in,
                              void* d_out, int out_size, void* d_ws, size_t ws_size,
                              hipStream_t stream) {
    const float* x     = (const float*)d_in[0];
    const int*   ei    = (const int*)d_in[1];   // [2, E] int32
    const float* ew    = (const float*)d_in[2];
    const float* Wenc  = (const float*)d_in[3];
    const float* Wdec  = (const float*)d_in[4];
    const float* gamma = (const float*)d_in[5];
    const float* beta  = (const float*)d_in[6];
    float* out = (float*)d_out;

    const int* src = ei;
    const int* dst = ei + N_EDGES;

    char* p = (char*)d_ws;
    auto carve = [&](size_t bytes) -> void* {
        void* r = (void*)p;
        p += (bytes + 255) & ~(size_t)255;
        return r;
    };
    int*  counts  = (int*)carve(SCAN_N * sizeof(int));
    int*  fillpos = (int*)carve(SCAN_N * sizeof(int));
    int*  row_off = (int*)carve(SCAN_N * sizeof(int));
    int*  bsum    = (int*)carve(SCAN_BLOCKS * sizeof(int));
    int2* ep      = (int2*)carve((size_t)EP_CAP * sizeof(int2));
    unsigned* H  = (unsigned*)carve((size_t)N_NODES * 64 * sizeof(unsigned));
    unsigned* ZA = (unsigned*)carve((size_t)N_NODES * 64 * sizeof(unsigned));
    unsigned* ZB = (unsigned*)carve((size_t)N_NODES * 64 * sizeof(unsigned));

    // CSR build (per launch; deterministic work each call)
    hipMemsetAsync(counts, 0, SCAN_N * sizeof(int), stream);
    hipMemsetAsync(ep, 0, (size_t)EP_CAP * sizeof(int2), stream);  // pads -> (0,0)
    count_k<<<(N_EDGES + 255) / 256, 256, 0, stream>>>(dst, counts);
    scan1_k<<<SCAN_BLOCKS, 1024, 0, stream>>>(counts, bsum);
    scan2_k<<<1, 128, 0, stream>>>(bsum);
    scan3_k<<<SCAN_BLOCKS, 1024, 0, stream>>>(counts, bsum, row_off, fillpos);
    bucket_k<<<(N_EDGES + 255) / 256, 256, 0, stream>>>(src, dst, ew, fillpos, ep);

    // Encoder
    encoder_k<<<512, 1024, 0, stream>>>(x, Wenc, gamma, beta, H);

    const int prop_blocks = (N_NODES + 3) / 4;   // 1 node/wave, 4 waves/block
    unsigned* bufs[2] = {ZA, ZB};
    for (int l = 0; l < NLAYERS; ++l) {
        const unsigned* zin = H;                  // x0 = H (layer input)
        for (int k = 0; k < KSTEPS; ++k) {
            int last = (k == KSTEPS - 1);
            unsigned* zout = last ? H : bufs[k & 1];
            prop_k<<<prop_blocks, 256, 0, stream>>>(zin, H, row_off, ep, zout,
                                                    last, gamma, beta);
            zin = zout;
        }
    }

    decoder_k<<<512, 1024, 0, stream>>>(H, Wdec, out);
}